// Round 7
// baseline (304.094 us; speedup 1.0000x reference)
//
#include <hip/hip_runtime.h>

#define DEV __device__ __forceinline__

typedef __attribute__((ext_vector_type(4))) float floatx4;
typedef __attribute__((ext_vector_type(8))) short short8;

DEV unsigned short f2bf(float f) {
  unsigned u = __float_as_uint(f);
  u += 0x7FFF + ((u >> 16) & 1);
  return (unsigned short)(u >> 16);
}
DEV float bf2f(unsigned short h) { return __uint_as_float(((unsigned)h) << 16); }

// pack two f32 -> bf16x2 dword (round-half-up) with one v_perm_b32
DEV unsigned pkbf(float lo, float hi) {
  return __builtin_amdgcn_perm(__float_as_uint(hi) + 0x8000u,
                               __float_as_uint(lo) + 0x8000u, 0x07060302u);
}

#if __has_builtin(__builtin_amdgcn_exp2f)
#define EXP2(x) __builtin_amdgcn_exp2f(x)
#else
#define EXP2(x) exp2f(x)
#endif

#define GLD16(g, l)                                                            \
  __builtin_amdgcn_global_load_lds(                                            \
      (const __attribute__((address_space(1))) void*)(g),                      \
      (__attribute__((address_space(3))) void*)(l), 16, 0, 0)

// ---------------------------------------------------------------- prep
__global__ void k_prep(const float* __restrict__ x, const float* __restrict__ pe,
                       const float* __restrict__ w0, const float* __restrict__ w1,
                       const float* __restrict__ w2, const float* __restrict__ w3,
                       unsigned short* __restrict__ wt, float* __restrict__ xf,
                       unsigned short* __restrict__ xb) {
  __shared__ float t[64][65];
  const int bid = blockIdx.x, tid = threadIdx.x;
  if (bid < 1024) {
    const int z = bid >> 8, rem = bid & 255;
    const int bx = rem & 15, by = rem >> 4;
    const int tx = tid & 63, ty = tid >> 6;
    const float* wsel = (z == 0) ? w0 : (z == 1) ? w1 : (z == 2) ? w2 : w3;
    unsigned short* out = wt + (size_t)z * 1048576;
    const int k0 = bx * 64, n0 = by * 64;
    for (int i = ty; i < 64; i += 4)
      t[i][tx] = wsel[(size_t)(k0 + i) * 1024 + n0 + tx];
    __syncthreads();
    for (int i = ty; i < 64; i += 4)
      out[(size_t)(n0 + i) * 1024 + k0 + tx] = f2bf(t[tx][i]);
  } else {
    const int idx = (bid - 1024) * 256 + tid;  // float4 index, 2M total
    const int row = idx >> 8;
    const int c4 = idx & 255;
    const int s = row & 2047;
    const float4 xv = ((const float4*)x)[idx];
    const float4 pv = ((const float4*)pe)[s * 256 + c4];
    float4 r;
    r.x = xv.x + pv.x; r.y = xv.y + pv.y; r.z = xv.z + pv.z; r.w = xv.w + pv.w;
    ((float4*)xf)[idx] = r;
    ushort4 o;
    o.x = f2bf(r.x); o.y = f2bf(r.y); o.z = f2bf(r.z); o.w = f2bf(r.w);
    ((ushort4*)xb)[idx] = o;
  }
}

// ---------------------------------------------------------------- GEMM core v2
// (used by gemmo) 128x128 block, wave 64x64, BK=64, XOR swizzle
#define GEMM_CORE(Aptr, Bptr, RB, CB)                                          \
  for (int k0 = 0; k0 < 1024; k0 += 64) {                                      \
    _Pragma("unroll") for (int r = 0; r < 4; ++r) {                            \
      const int c = r * 256 + tid;                                             \
      const int rw = c >> 3;                                                   \
      const int gc = ((c & 7) ^ (rw & 7)) << 3;                                \
      GLD16((Aptr) + (size_t)((RB) + rw) * 1024 + k0 + gc,                     \
            As + (size_t)(r * 256 + wave * 64) * 8);                           \
      GLD16((Bptr) + (size_t)((CB) + rw) * 1024 + k0 + gc,                     \
            Bs + (size_t)(r * 256 + wave * 64) * 8);                           \
    }                                                                          \
    __syncthreads();                                                           \
    _Pragma("unroll") for (int kk = 0; kk < 2; ++kk) {                         \
      short8 fa[4], fb[4];                                                     \
      _Pragma("unroll") for (int i = 0; i < 4; ++i) {                          \
        fa[i] = *(const short8*)(As + (wm * 64 + i * 16 + l16) * 64 +          \
                                 (((kk * 4 + quad) ^ (l16 & 7)) << 3));        \
        fb[i] = *(const short8*)(Bs + (wn * 64 + i * 16 + l16) * 64 +          \
                                 (((kk * 4 + quad) ^ (l16 & 7)) << 3));        \
      }                                                                        \
      _Pragma("unroll") for (int mi = 0; mi < 4; ++mi)                         \
          _Pragma("unroll") for (int ni = 0; ni < 4; ++ni) acc[mi][ni] =       \
          __builtin_amdgcn_mfma_f32_16x16x32_bf16(fa[mi], fb[ni],              \
                                                  acc[mi][ni], 0, 0, 0);       \
    }                                                                          \
    __syncthreads();                                                           \
  }

// ---------------------------------------------------------------- GEMM core v3
// 256(M)x128(N) block, wave-tile 128x64 (acc[8][4]): 24 b128 LDS reads per
// 64 MFMA per K64-iter -> LDS-pipe ~288 cyc vs MFMA ~310 cyc (balanced,
// vs 2x LDS-oversubscribed at 64x64/wave). 2 waves/SIMD.
#define GEMM_CORE_V3(Aptr, Bptr, RB, CB)                                       \
  for (int k0 = 0; k0 < 1024; k0 += 64) {                                      \
    _Pragma("unroll") for (int r = 0; r < 8; ++r) {                            \
      const int c = r * 256 + tid;                                             \
      const int rw = c >> 3;                                                   \
      const int gc = ((c & 7) ^ (rw & 7)) << 3;                                \
      GLD16((Aptr) + (size_t)((RB) + rw) * 1024 + k0 + gc,                     \
            As + (size_t)(r * 256 + wave * 64) * 8);                           \
    }                                                                          \
    _Pragma("unroll") for (int r = 0; r < 4; ++r) {                            \
      const int c = r * 256 + tid;                                             \
      const int rw = c >> 3;                                                   \
      const int gc = ((c & 7) ^ (rw & 7)) << 3;                                \
      GLD16((Bptr) + (size_t)((CB) + rw) * 1024 + k0 + gc,                     \
            Bs + (size_t)(r * 256 + wave * 64) * 8);                           \
    }                                                                          \
    __syncthreads();                                                           \
    _Pragma("unroll") for (int kk = 0; kk < 2; ++kk) {                         \
      short8 fa[8], fb[4];                                                     \
      _Pragma("unroll") for (int i = 0; i < 8; ++i)                            \
        fa[i] = *(const short8*)(As + (wm * 128 + i * 16 + l16) * 64 +         \
                                 (((kk * 4 + quad) ^ (l16 & 7)) << 3));        \
      _Pragma("unroll") for (int i = 0; i < 4; ++i)                            \
        fb[i] = *(const short8*)(Bs + (wn * 64 + i * 16 + l16) * 64 +          \
                                 (((kk * 4 + quad) ^ (l16 & 7)) << 3));        \
      _Pragma("unroll") for (int mi = 0; mi < 8; ++mi)                         \
          _Pragma("unroll") for (int ni = 0; ni < 4; ++ni) acc[mi][ni] =       \
          __builtin_amdgcn_mfma_f32_16x16x32_bf16(fa[mi], fb[ni],              \
                                                  acc[mi][ni], 0, 0, 0);       \
    }                                                                          \
    __syncthreads();                                                           \
  }

// ---------------------------------------------------------------- QKV GEMMs v3
// blocks 0..511: C[8192,2048] = xpeb . (wq|wk)^T -> q,k as [b,h,s,d]
// blocks 512..767: Vt[1024,8192] = wt_v . xpeb^T -> [b,h,d,s]
// XCD-banded for L2 locality; 768 blocks, 2 blocks/CU.
__global__ __launch_bounds__(256, 2) void k_gemmqkvt(
    const unsigned short* __restrict__ xpeb, const unsigned short* __restrict__ wt,
    const float* __restrict__ bqp, const float* __restrict__ bkp,
    const float* __restrict__ bvp, unsigned short* __restrict__ qb,
    unsigned short* __restrict__ kb, unsigned short* __restrict__ vtb) {
  __shared__ unsigned short As[256 * 64];
  __shared__ unsigned short Bs[128 * 64];
  const int tid = threadIdx.x;
  const int lane = tid & 63, wave = tid >> 6;
  const int quad = lane >> 4, l16 = lane & 15;
  const int wm = wave >> 1, wn = wave & 1;
  const int id = blockIdx.x;

  floatx4 acc[8][4];
  const floatx4 vzero = {0.f, 0.f, 0.f, 0.f};
#pragma unroll
  for (int i = 0; i < 8; ++i)
#pragma unroll
    for (int j = 0; j < 4; ++j) acc[i][j] = vzero;

  if (id < 512) {
    const int xcd = id & 7, j = id >> 3;
    const int bx = (xcd << 2) | (j & 3), by = j >> 2;  // bx 0..31, by 0..15
    const int rb = bx * 256, cb = by * 128;
    GEMM_CORE_V3(xpeb, wt, rb, cb);
    const int which = cb >> 10;  // 0=q 1=k
    const float* bias = (which == 0) ? bqp : bkp;
    unsigned short* out = (which == 0) ? qb : kb;
#pragma unroll
    for (int ni = 0; ni < 4; ++ni) {
      const int col = cb + wn * 64 + ni * 16 + l16;
      const int cl = col & 1023;
      const float bvv = bias[cl];
      const int h = cl >> 6, d = cl & 63;
#pragma unroll
      for (int mi = 0; mi < 8; ++mi) {
#pragma unroll
        for (int r = 0; r < 4; ++r) {
          const int row = rb + wm * 128 + mi * 16 + quad * 4 + r;
          const int b = row >> 11, s = row & 2047;
          out[((size_t)(b * 16 + h) * 2048 + s) * 64 + d] = f2bf(acc[mi][ni][r] + bvv);
        }
      }
    }
  } else {
    const int id2 = id - 512;  // 0..255
    const int xcd = id2 & 7, j = id2 >> 3;
    const int by = (xcd << 3) | (j & 7), bx = j >> 3;  // by 0..63 token, bx 0..3 d_out
    const int rb = bx * 256, cb = by * 128;
    GEMM_CORE_V3(wt + 2097152, xpeb, rb, cb);
#pragma unroll
    for (int mi = 0; mi < 8; ++mi) {
#pragma unroll
      for (int r = 0; r < 4; ++r) {
        const int row = rb + wm * 128 + mi * 16 + quad * 4 + r;  // d_out = h*64+d
        const float bvv = bvp[row];
#pragma unroll
        for (int ni = 0; ni < 4; ++ni) {
          const int col = cb + wn * 64 + ni * 16 + l16;  // token
          vtb[((size_t)(col >> 11) * 1024 + row) * 2048 + (col & 2047)] =
              f2bf(acc[mi][ni][r] + bvv);
        }
      }
    }
  }
}

// ---------------------------------------------------------------- out-proj GEMM
__global__ __launch_bounds__(256, 4) void k_gemmo(
    const unsigned short* __restrict__ A, const unsigned short* __restrict__ Bt,
    const float* __restrict__ bias, unsigned short* __restrict__ out) {
  __shared__ unsigned short As[128 * 64];
  __shared__ unsigned short Bs[128 * 64];
  const int tid = threadIdx.x;
  const int lane = tid & 63, wave = tid >> 6;
  const int quad = lane >> 4, l16 = lane & 15;
  const int wm = wave >> 1, wn = wave & 1;
  const int id = blockIdx.x;  // 0..511
  const int xcd = id & 7, j = id >> 3;
  const int bx = (xcd << 3) | (j & 7), by = j >> 3;  // bx 0..63, by 0..7
  const int rb = bx * 128, cb = by * 128;

  floatx4 acc[4][4];
  const floatx4 vzero = {0.f, 0.f, 0.f, 0.f};
#pragma unroll
  for (int i = 0; i < 4; ++i)
#pragma unroll
    for (int jj = 0; jj < 4; ++jj) acc[i][jj] = vzero;

  GEMM_CORE(A, Bt, rb, cb);

#pragma unroll
  for (int ni = 0; ni < 4; ++ni) {
    const int col = cb + wn * 64 + ni * 16 + l16;
    const float bvv = bias[col];
#pragma unroll
    for (int mi = 0; mi < 4; ++mi) {
#pragma unroll
      for (int r = 0; r < 4; ++r) {
        const int row = rb + wm * 64 + mi * 16 + quad * 4 + r;
        out[(size_t)row * 1024 + col] = f2bf(acc[mi][ni][r] + bvv);
      }
    }
  }
}

// ---------------------------------------------------------------- flash attn v6
// 64 q-rows per wave (256 per block), grid 512 = 2 blocks/CU uniform.
// K/V/fragment LDS reads amortized over 2x the q-work vs v5.
__global__ __launch_bounds__(256, 2) void k_flash(
    const unsigned short* __restrict__ Q, const unsigned short* __restrict__ Kb,
    const unsigned short* __restrict__ Vt, unsigned short* __restrict__ AO) {
  __shared__ unsigned short Ks[64 * 64];
  __shared__ unsigned short Vs[64 * 64];
  __shared__ unsigned short Ps[4][64 * 72];
  const int tid = threadIdx.x, lane = tid & 63, wave = tid >> 6;
  const int quad = lane >> 4, l16 = lane & 15;
  const int g = blockIdx.x;            // 0..511
  const int li = g >> 3;               // 0..63
  const int bh = (g & 7) * 8 + (li >> 3);
  const int qt = li & 7;               // 256-row q block
  const int b = bh >> 4, h = bh & 15;

  const unsigned short* Kh = Kb + (size_t)bh * 2048 * 64;
  const unsigned short* Vh = Vt + (size_t)bh * 64 * 2048;

  const float LAMBDA = 0.125f * 1.4426950408889634f;
  short8 aq[4][2];
  {
    const unsigned short* Qb = Q + ((size_t)bh * 2048 + qt * 256 + wave * 64) * 64;
#pragma unroll
    for (int qi = 0; qi < 4; ++qi)
#pragma unroll
      for (int c = 0; c < 2; ++c) {
        const short8 raw =
            *(const short8*)(Qb + (size_t)(qi * 16 + l16) * 64 + c * 32 + quad * 8);
        short8 sv;
#pragma unroll
        for (int j = 0; j < 8; ++j)
          sv[j] = (short)f2bf(bf2f((unsigned short)raw[j]) * LAMBDA);
        aq[qi][c] = sv;
      }
  }

  short8 onesv;  // bf16 1.0 in all 8 slots
#pragma unroll
  for (int j = 0; j < 8; ++j) onesv[j] = (short)0x3F80;

  const floatx4 vzero = {0.f, 0.f, 0.f, 0.f};
  floatx4 o[4][4];
#pragma unroll
  for (int qi = 0; qi < 4; ++qi)
#pragma unroll
    for (int di = 0; di < 4; ++di) o[qi][di] = vzero;
  floatx4 lacc[4] = {vzero, vzero, vzero, vzero};
  unsigned short* Pw = Ps[wave];

#define STAGE(ktile)                                                           \
  {                                                                            \
    _Pragma("unroll") for (int r = 0; r < 2; ++r) {                            \
      const int c = r * 256 + tid;                                             \
      const int rw = c >> 3;                                                   \
      const int gc = ((c & 7) ^ (rw & 7)) * 8;                                 \
      GLD16(Kh + (size_t)((ktile) * 64 + rw) * 64 + gc,                        \
            &Ks[(size_t)(r * 256 + wave * 64) * 8]);                           \
      GLD16(Vh + (size_t)rw * 2048 + (ktile) * 64 + gc,                        \
            &Vs[(size_t)(r * 256 + wave * 64) * 8]);                           \
    }                                                                          \
  }

  STAGE(0);
  __syncthreads();

  for (int kt = 0; kt < 32; ++kt) {
    short8 fk[4][2];
#pragma unroll
    for (int ni = 0; ni < 4; ++ni)
#pragma unroll
      for (int c = 0; c < 2; ++c)
        fk[ni][c] = *(const short8*)(&Ks[(ni * 16 + l16) * 64 +
                                         (((c * 4 + quad) ^ (l16 & 7)) << 3)]);

#pragma unroll
    for (int qi = 0; qi < 4; ++qi) {
      floatx4 p[4];
#pragma unroll
      for (int ni = 0; ni < 4; ++ni) {
        floatx4 t = vzero;
#pragma unroll
        for (int c = 0; c < 2; ++c)
          t = __builtin_amdgcn_mfma_f32_16x16x32_bf16(fk[ni][c], aq[qi][c], t, 0, 0, 0);
        p[ni] = t;
      }
#pragma unroll
      for (int ni = 0; ni < 4; ++ni)
#pragma unroll
        for (int r = 0; r < 4; ++r) p[ni][r] = EXP2(p[ni][r]);
#pragma unroll
      for (int ni = 0; ni < 4; ++ni) {
        uint2 pk;
        pk.x = pkbf(p[ni][0], p[ni][1]);
        pk.y = pkbf(p[ni][2], p[ni][3]);
        *(uint2*)(&Pw[(qi * 16 + l16) * 72 + ni * 16 + quad * 4]) = pk;
      }
    }
    asm volatile("s_waitcnt lgkmcnt(0)" ::: "memory");  // per-wave DS in-order

#pragma unroll
    for (int c = 0; c < 2; ++c) {
      short8 ap[4];
#pragma unroll
      for (int qi = 0; qi < 4; ++qi)
        ap[qi] = *(const short8*)(&Pw[(qi * 16 + l16) * 72 + c * 32 + quad * 8]);
#pragma unroll
      for (int qi = 0; qi < 4; ++qi)
        lacc[qi] = __builtin_amdgcn_mfma_f32_16x16x32_bf16(ap[qi], onesv, lacc[qi], 0, 0, 0);
#pragma unroll
      for (int di = 0; di < 4; ++di) {
        const short8 fv = *(const short8*)(&Vs[(di * 16 + l16) * 64 +
                                               (((c * 4 + quad) ^ (l16 & 7)) << 3)]);
#pragma unroll
        for (int qi = 0; qi < 4; ++qi)
          o[qi][di] = __builtin_amdgcn_mfma_f32_16x16x32_bf16(ap[qi], fv, o[qi][di], 0, 0, 0);
      }
    }
    __syncthreads();                   // all waves done reading tile kt
    if (kt + 1 < 32) STAGE(kt + 1);
    __syncthreads();                   // staged tile kt+1 resident
  }

#pragma unroll
  for (int qi = 0; qi < 4; ++qi) {
    float invl[4];
#pragma unroll
    for (int r = 0; r < 4; ++r) invl[r] = __builtin_amdgcn_rcpf(lacc[qi][r]);
#pragma unroll
    for (int di = 0; di < 4; ++di) {
#pragma unroll
      for (int r = 0; r < 4; ++r) {
        const int s = qt * 256 + wave * 64 + qi * 16 + quad * 4 + r;
        const int col = h * 64 + di * 16 + l16;
        AO[((size_t)b * 2048 + s) * 1024 + col] = f2bf(o[qi][di][r] * invl[r]);
      }
    }
  }
#undef STAGE
}

// ---------------------------------------------------------------- residual+LN
__global__ __launch_bounds__(256) void k_ln(
    const unsigned short* __restrict__ proj, const float* __restrict__ xpe,
    const float* __restrict__ gamma, const float* __restrict__ beta,
    float* __restrict__ out) {
  const int row = blockIdx.x, tid = threadIdx.x;
  const int lane = tid & 63, wave = tid >> 6;
  const float4 xv = ((const float4*)(xpe + (size_t)row * 1024))[tid];
  const ushort4 pv = ((const ushort4*)(proj + (size_t)row * 1024))[tid];
  const float h0 = xv.x + bf2f(pv.x);
  const float h1 = xv.y + bf2f(pv.y);
  const float h2 = xv.z + bf2f(pv.z);
  const float h3 = xv.w + bf2f(pv.w);
  float s = h0 + h1 + h2 + h3;
  float s2 = h0 * h0 + h1 * h1 + h2 * h2 + h3 * h3;
#pragma unroll
  for (int m = 1; m < 64; m <<= 1) {
    s += __shfl_xor(s, m);
    s2 += __shfl_xor(s2, m);
  }
  __shared__ float rs[4], rq[4];
  if (lane == 0) { rs[wave] = s; rq[wave] = s2; }
  __syncthreads();
  s = rs[0] + rs[1] + rs[2] + rs[3];
  s2 = rq[0] + rq[1] + rq[2] + rq[3];
  const float mu = s * (1.f / 1024.f);
  const float var = s2 * (1.f / 1024.f) - mu * mu;
  const float rstd = rsqrtf(var + 1e-5f);
  const float4 gv = ((const float4*)gamma)[tid];
  const float4 bvv = ((const float4*)beta)[tid];
  float4 ov;
  ov.x = (h0 - mu) * rstd * gv.x + bvv.x;
  ov.y = (h1 - mu) * rstd * gv.y + bvv.y;
  ov.z = (h2 - mu) * rstd * gv.z + bvv.z;
  ov.w = (h3 - mu) * rstd * gv.w + bvv.w;
  ((float4*)(out + (size_t)row * 1024))[tid] = ov;
}

// ---------------------------------------------------------------- launch
extern "C" void kernel_launch(void* const* d_in, const int* in_sizes, int n_in,
                              void* d_out, int out_size, void* d_ws, size_t ws_size,
                              hipStream_t stream) {
  const float* x = (const float*)d_in[0];
  const float* wq = (const float*)d_in[1];
  const float* bq = (const float*)d_in[2];
  const float* wk = (const float*)d_in[3];
  const float* bk = (const float*)d_in[4];
  const float* wv = (const float*)d_in[5];
  const float* bv = (const float*)d_in[6];
  const float* wo = (const float*)d_in[7];
  const float* bo = (const float*)d_in[8];
  const float* gamma = (const float*)d_in[9];
  const float* beta = (const float*)d_in[10];
  const float* pe = (const float*)d_in[11];

  if (ws_size < 125829120) return;  // need 120 MB scratch

  char* w = (char*)d_ws;
  unsigned short* wt = (unsigned short*)(w);               // 4x 1024x1024 bf16 (8 MB)
  float* xpef = (float*)(w + 8388608);                     // 8192x1024 f32 (32 MB)
  unsigned short* xpeb = (unsigned short*)(w + 41943040);  // 8192x1024 bf16 (16 MB)
  unsigned short* qb = (unsigned short*)(w + 58720256);    // 16 MB
  unsigned short* kb = (unsigned short*)(w + 75497472);    // 16 MB
  unsigned short* vtb = (unsigned short*)(w + 92274688);   // 16 MB
  unsigned short* aob = (unsigned short*)(w + 109051904);  // 16 MB
  unsigned short* projb = qb;                              // alias: Q dead after flash

  k_prep<<<9216, 256, 0, stream>>>(x, pe, wq, wk, wv, wo, wt, xpef, xpeb);
  k_gemmqkvt<<<768, 256, 0, stream>>>(xpeb, wt, bq, bk, bv, qb, kb, vtb);
  k_flash<<<512, 256, 0, stream>>>(qb, kb, vtb, aob);
  k_gemmo<<<512, 256, 0, stream>>>(aob, wt + 3145728, bo, projb);
  k_ln<<<8192, 256, 0, stream>>>(projb, xpef, gamma, beta, (float*)d_out);
}